// Round 3
// baseline (167.092 us; speedup 1.0000x reference)
//
#include <hip/hip_runtime.h>

// GQA block. B=2, T=2048, C=1024, H=16, KV=8 (GROUP=2), D=64.
// Round 9: gemm N-tile 64 -> 128 (m97-class 128x128 tile, BK=64).
//  - Per wave: 64m x 64n, acc[4][4], 32 MFMA : 16 ds_read_b128 per K-step.
//  - Staging: 32 groups x 1 KB via global_load_lds w16, chunk-XOR swizzle
//    on the global source side (LDS linear). LDS 32 KB.
//  - K-loop order unchanged -> bit-identical outputs vs round 8.
//  - attn4 (KVBLK=128, register-resident P, setprio) unchanged.

#define SEQ    2048
#define CDIM   1024
#define KVDIM  512
#define SCL2E  0.18033688011112042f   // 0.125 * log2(e)

typedef __attribute__((ext_vector_type(8))) short   bf16x8;
typedef __attribute__((ext_vector_type(4))) float   f32x4;
typedef unsigned short ushort_t;

__device__ __forceinline__ ushort_t f2bf(float f) {
    unsigned u = __float_as_uint(f);
    u += 0x7FFFu + ((u >> 16) & 1u);
    return (ushort_t)(u >> 16);
}
__device__ __forceinline__ float bf2f(ushort_t h) {
    return __uint_as_float(((unsigned)h) << 16);
}
__device__ __forceinline__ void load_lds16(const void* g, void* l) {
    __builtin_amdgcn_global_load_lds(
        (const __attribute__((address_space(1))) void*)g,
        (__attribute__((address_space(3))) void*)l, 16, 0, 0);
}

// ---------------------------------------------------------------------------
// all five inputs -> bf16 hi, one launch. grid 7168 x 256 (exact).
// ---------------------------------------------------------------------------
__global__ __launch_bounds__(256) void cvt_bf16(
    const float* __restrict__ x,  const float* __restrict__ wq,
    const float* __restrict__ wk, const float* __restrict__ wv,
    const float* __restrict__ wp,
    ushort_t* __restrict__ xh,  ushort_t* __restrict__ wqh,
    ushort_t* __restrict__ wkh, ushort_t* __restrict__ wvh,
    ushort_t* __restrict__ wph)
{
    const int i = blockIdx.x * 256 + threadIdx.x;
    const float* src; ushort_t* dst; int off;
    if (i < 1048576)      { src = x;  dst = xh;  off = i; }
    else if (i < 1310720) { src = wq; dst = wqh; off = i - 1048576; }
    else if (i < 1441792) { src = wk; dst = wkh; off = i - 1310720; }
    else if (i < 1572864) { src = wv; dst = wvh; off = i - 1441792; }
    else                  { src = wp; dst = wph; off = i - 1572864; }
    const float4 v = ((const float4*)src)[off];
    ushort4 h;
    h.x = f2bf(v.x); h.y = f2bf(v.y); h.z = f2bf(v.z); h.w = f2bf(v.w);
    ((ushort4*)dst)[off] = h;
}

// ---------------------------------------------------------------------------
// bf16 MFMA GEMM, C = A*B^T, 1 product. Tile 128(M) x 128(N), BK=64, 256 thr.
// Waves 2x2 over tile (64m x 64n each). LDS rows xor-swizzled in 16B chunks
// (inverse swizzle applied on global source side for global_load_lds).
// Up to 3 fused outputs along N (each N a multiple of 128).
// epi: 0 = fp32; 3 = bf16 hi * scale.
// ---------------------------------------------------------------------------
__global__ __launch_bounds__(256, 2) void gemm128(
    const ushort_t* __restrict__ A, int K,
    const ushort_t* __restrict__ B1, void* __restrict__ C1, int N1, int epi1, float sc1,
    const ushort_t* __restrict__ B2, void* __restrict__ C2, int N2, int epi2, float sc2,
    const ushort_t* __restrict__ B3, void* __restrict__ C3, int N3, int epi3, float sc3)
{
    __shared__ ushort_t sA[128 * 64];   // 16 KB
    __shared__ ushort_t sB[128 * 64];   // 16 KB

    const int tid = threadIdx.x, wv = tid >> 6, lane = tid & 63;
    const int lm = lane & 15, quad = lane >> 4;
    const int m0 = blockIdx.y * 128;

    const int t1 = N1 >> 7, t2 = N2 >> 7;
    const int bx = blockIdx.x;
    const ushort_t* B; void* Cv; int n0, Nout, epi; float sc;
    if (bx < t1)           { B = B1; Cv = C1; Nout = N1; epi = epi1; sc = sc1; n0 = bx * 128; }
    else if (bx < t1 + t2) { B = B2; Cv = C2; Nout = N2; epi = epi2; sc = sc2; n0 = (bx - t1) * 128; }
    else                   { B = B3; Cv = C3; Nout = N3; epi = epi3; sc = sc3; n0 = (bx - t1 - t2) * 128; }

    const int mh = wv >> 1, nh = wv & 1;
    const int srow = lane >> 3;
    const int scol = ((lane & 7) ^ ((lane >> 3) & 7)) * 8;

    f32x4 acc[4][4] = {};

    for (int k0 = 0; k0 < K; k0 += 64) {
        __syncthreads();
        #pragma unroll
        for (int i = 0; i < 8; ++i) {
            const int g = wv * 8 + i;       // 0..15 -> A groups, 16..31 -> B groups
            if (g < 16)
                load_lds16(A + (size_t)(m0 + g * 8 + srow) * K + k0 + scol, sA + g * 512);
            else
                load_lds16(B + (size_t)(n0 + (g - 16) * 8 + srow) * K + k0 + scol, sB + (g - 16) * 512);
        }
        __syncthreads();

        #pragma unroll
        for (int ks = 0; ks < 2; ++ks) {
            const int co = ((ks * 4 + quad) ^ (lm & 7)) * 8;
            bf16x8 a[4], b[4];
            #pragma unroll
            for (int mt = 0; mt < 4; ++mt)
                a[mt] = *(const bf16x8*)&sA[(mh * 64 + mt * 16 + lm) * 64 + co];
            #pragma unroll
            for (int nt = 0; nt < 4; ++nt)
                b[nt] = *(const bf16x8*)&sB[(nh * 64 + nt * 16 + lm) * 64 + co];
            #pragma unroll
            for (int mt = 0; mt < 4; ++mt)
                #pragma unroll
                for (int nt = 0; nt < 4; ++nt)
                    acc[mt][nt] = __builtin_amdgcn_mfma_f32_16x16x32_bf16(a[mt], b[nt], acc[mt][nt], 0, 0, 0);
        }
    }

    // C/D: row = m + quad*4 + reg, col = n + lm
    if (epi == 0) {
        float* C = (float*)Cv;
        #pragma unroll
        for (int mt = 0; mt < 4; ++mt)
            #pragma unroll
            for (int nt = 0; nt < 4; ++nt)
                #pragma unroll
                for (int r = 0; r < 4; ++r)
                    C[(size_t)(m0 + mh * 64 + mt * 16 + quad * 4 + r) * Nout + n0 + nh * 64 + nt * 16 + lm]
                        = acc[mt][nt][r];
    } else {
        ushort_t* C = (ushort_t*)Cv;
        #pragma unroll
        for (int mt = 0; mt < 4; ++mt)
            #pragma unroll
            for (int nt = 0; nt < 4; ++nt)
                #pragma unroll
                for (int r = 0; r < 4; ++r)
                    C[(size_t)(m0 + mh * 64 + mt * 16 + quad * 4 + r) * Nout + n0 + nh * 64 + nt * 16 + lm]
                        = f2bf(acc[mt][nt][r] * sc);
    }
}

// ---------------------------------------------------------------------------
// v (fp32, [b*2048+t][512]) -> vth (bf16, [(b*8+kv)*64 + d][2048])
// ---------------------------------------------------------------------------
__global__ __launch_bounds__(256) void vtrans_kernel(
    const float* __restrict__ v, ushort_t* __restrict__ vt)
{
    __shared__ float tile[64][65];
    const int t0  = blockIdx.x * 64;
    const int bkv = blockIdx.y;
    const int r   = threadIdx.x >> 2;
    const int c0  = (threadIdx.x & 3) * 16;

    const float* src = v + (size_t)((bkv >> 3) * SEQ + t0 + r) * KVDIM + (bkv & 7) * 64 + c0;
    #pragma unroll
    for (int i = 0; i < 4; ++i) {
        const float4 f = *(const float4*)(src + i * 4);
        tile[r][c0 + i*4 + 0] = f.x;
        tile[r][c0 + i*4 + 1] = f.y;
        tile[r][c0 + i*4 + 2] = f.z;
        tile[r][c0 + i*4 + 3] = f.w;
    }
    __syncthreads();
    ushort_t* dst = vt + (size_t)(bkv * 64 + r) * SEQ + t0 + c0;
    #pragma unroll
    for (int i = 0; i < 4; ++i) {
        ushort4 u;
        u.x = f2bf(tile[c0 + i*4 + 0][r]);
        u.y = f2bf(tile[c0 + i*4 + 1][r]);
        u.z = f2bf(tile[c0 + i*4 + 2][r]);
        u.w = f2bf(tile[c0 + i*4 + 3][r]);
        *(ushort4*)(dst + i * 4) = u;
    }
}

// ---------------------------------------------------------------------------
// MFMA flash attention, fixed m=0 softmax, all-bf16 operands, fp32 acc.
// grid (SEQ/128, B*NHEAD), 256 threads. Wave w: q rows [t0+w*32, +32)
// as 2 groups of 16 (Q-hi B-frags in registers, pre-scaled by 0.125*log2e).
// Double-buffered K/V staging, ONE barrier per 128-row K-tile (16 total).
//
// K tile [128 s][64 d], LDS row rho holds global K row sigma(rho):
//   rho bits [sti2 sti1 sti0 q1 q0 r1 r0] -> sigma = [sti2 sti1 q1 q0 sti0 r1 r0]
// so the S^T C-layout delivers exactly the PV A-fragment content: hardware
// k-slot kappa = 32ks+8quad+j holds logical s = kappa. P never leaves
// registers: exp2 -> v_perm bf16-truncate -> packed bf16x8 A operands.
// V tile [64 d][128 s] (16 chunks of 16B per row), chunk stored at
// position c ^ (d&7); inverse applied on global source side.
// ---------------------------------------------------------------------------
__global__ __launch_bounds__(256, 2) void attn4(
    const ushort_t* __restrict__ Qh, const ushort_t* __restrict__ Kh,
    const ushort_t* __restrict__ Vth, ushort_t* __restrict__ Yh)
{
    __shared__ ushort_t sK[2][128 * 64];   // 32 KB
    __shared__ ushort_t sV[2][64 * 128];   // 32 KB

    const int tid = threadIdx.x, wv = tid >> 6, lane = tid & 63;
    const int lm = lane & 15, quad = lane >> 4;
    const int b = blockIdx.y >> 4, h = blockIdx.y & 15, kvh = h >> 1;
    const int t0 = blockIdx.x * 128, tq0 = t0 + wv * 32;

    // persistent Q B-frags: n = q = lm (per group), k = d = ks*32 + quad*8 + j
    bf16x8 qh[2][2];
    #pragma unroll
    for (int qg = 0; qg < 2; ++qg) {
        const size_t rb = (size_t)(b * SEQ + tq0 + qg * 16 + lm) * CDIM + h * 64;
        #pragma unroll
        for (int ks = 0; ks < 2; ++ks)
            qh[qg][ks] = *(const bf16x8*)(Qh + rb + ks * 32 + quad * 8);
    }

    const ushort_t* gK = Kh  + (size_t)b * SEQ * KVDIM + kvh * 64;
    const ushort_t* gV = Vth + (size_t)(b * 8 + kvh) * 64 * SEQ;

    const int g0 = (wv & 1) * 8;          // group base within this wave's half

    // K staging lane geometry: 16 groups of (8 rows x 64 cols) = 512 ushorts
    const int srow = lane >> 3;           // 0..7 row within group
    const int scol = ((lane & 7) ^ ((lane >> 3) & 7)) * 8;  // swizzled 16B chunk

    // sigma-permuted source rows for K staging (LDS row -> global row)
    int krow[8];
    #pragma unroll
    for (int it = 0; it < 8; ++it) {
        const int lr = (g0 + it) * 8 + srow;   // 0..127
        krow[it] = (lr & 0x60) | ((lr & 0x10) >> 2) | ((lr & 0x0C) << 1) | (lr & 3);
    }

    // V staging lane geometry: 16 groups of (4 rows x 128 cols) = 512 ushorts
    const int vrow = lane >> 4;           // 0..3 row (d) within group
    const int vpos = lane & 15;           // 16B chunk position within row

    float l_a[2] = {0.0f, 0.0f}, l_b[2] = {0.0f, 0.0f};
    f32x4 O[2][4] = {};

    // preload tile 0 into buffer 0
    if (wv < 2) {
        #pragma unroll
        for (int it = 0; it < 8; ++it)
            load_lds16(gK + (size_t)krow[it] * KVDIM + scol,
                       &sK[0][(g0 + it) * 512]);
    } else {
        #pragma unroll
        for (int it = 0; it < 8; ++it) {
            const int d = (g0 + it) * 4 + vrow;
            load_lds16(gV + (size_t)d * SEQ + (vpos ^ (d & 7)) * 8,
                       &sV[0][(g0 + it) * 512]);
        }
    }

    typedef union { bf16x8 v; unsigned u[4]; } pku;

    for (int kt = 0; kt < SEQ / 128; ++kt) {
        const int cur = kt & 1;
        __syncthreads();   // tile kt landed; all waves done with buf cur^1

        if (kt + 1 < SEQ / 128) {
            const int s1 = (kt + 1) * 128;
            if (wv < 2) {
                #pragma unroll
                for (int it = 0; it < 8; ++it)
                    load_lds16(gK + (size_t)(s1 + krow[it]) * KVDIM + scol,
                               &sK[cur ^ 1][(g0 + it) * 512]);
            } else {
                #pragma unroll
                for (int it = 0; it < 8; ++it) {
                    const int d = (g0 + it) * 4 + vrow;
                    load_lds16(gV + (size_t)d * SEQ + s1 + (vpos ^ (d & 7)) * 8,
                               &sV[cur ^ 1][(g0 + it) * 512]);
                }
            }
        }

        // S^T = K Q^T : col = q = lm, row(lds) = sti*16 + quad*4 + r,
        // logical s = sigma(row)
        f32x4 st[2][8] = {};
        __builtin_amdgcn_s_setprio(1);
        #pragma unroll
        for (int sti = 0; sti < 8; ++sti)
            #pragma unroll
            for (int ks = 0; ks < 2; ++ks) {
                const int off = (sti * 16 + lm) * 64 + (((ks * 4 + quad) ^ (lm & 7)) * 8);
                const bf16x8 kf = *(const bf16x8*)&sK[cur][off];
                #pragma unroll
                for (int qg = 0; qg < 2; ++qg)
                    st[qg][sti] = __builtin_amdgcn_mfma_f32_16x16x32_bf16(kf, qh[qg][ks], st[qg][sti], 0, 0, 0);
            }
        __builtin_amdgcn_s_setprio(0);

        // P = exp2(S'), accumulate l, pack bf16 (truncate via v_perm)
        // directly into PV A-frags: pa[ks] elem j = 4*(sti&1)+r <- st[2ks+(sti&1)][r]
        pku pa[2][4];
        #pragma unroll
        for (int qg = 0; qg < 2; ++qg)
            #pragma unroll
            for (int sti = 0; sti < 8; ++sti) {
                const float p0 = __builtin_amdgcn_exp2f(st[qg][sti][0]);
                const float p1 = __builtin_amdgcn_exp2f(st[qg][sti][1]);
                const float p2 = __builtin_amdgcn_exp2f(st[qg][sti][2]);
                const float p3 = __builtin_amdgcn_exp2f(st[qg][sti][3]);
                if (sti & 1) l_b[qg] += (p0 + p1) + (p2 + p3);
                else         l_a[qg] += (p0 + p1) + (p2 + p3);
                pa[qg][sti >> 1].u[(sti & 1) * 2 + 0] =
                    __builtin_amdgcn_perm(__float_as_uint(p1), __float_as_uint(p0), 0x07060302u);
                pa[qg][sti >> 1].u[(sti & 1) * 2 + 1] =
                    __builtin_amdgcn_perm(__float_as_uint(p3), __float_as_uint(p2), 0x07060302u);
            }

        // O += P V : A = P (m=q, k-slot kappa holds s=kappa), B = V^T (n=d)
        __builtin_amdgcn_s_setprio(1);
        #pragma unroll
        for (int ks = 0; ks < 4; ++ks) {
            const int co = ((ks * 4 + quad) ^ (lm & 7)) * 8;
            #pragma unroll
            for (int dt = 0; dt < 4; ++dt) {
                const bf16x8 vt = *(const bf16x8*)&sV[cur][(dt * 16 + lm) * 128 + co];
                #pragma unroll
                for (int qg = 0; qg < 2; ++qg)
                    O[qg][dt] = __builtin_amdgcn_mfma_f32_16x16x32_bf16(pa[qg][ks].v, vt, O[qg][dt], 0, 0, 0);
            }
        }
        __builtin_amdgcn_s_setprio(0);
    }

    // l: reduce across quads (disjoint 32-row s slices per quad; sigma is a
    // bijection so coverage of each 128-row tile is exact)
    float l_r[2];
    #pragma unroll
    for (int qg = 0; qg < 2; ++qg) {
        l_r[qg] = l_a[qg] + l_b[qg];
        l_r[qg] += __shfl_xor(l_r[qg], 16);
        l_r[qg] += __shfl_xor(l_r[qg], 32);
    }
    // O C-layout: col = d = dt*16 + lm, row = q = qg*16 + quad*4 + r
    #pragma unroll
    for (int qg = 0; qg < 2; ++qg)
        #pragma unroll
        for (int r = 0; r < 4; ++r) {
            const float lq = __shfl(l_r[qg], (lane & 48) | (quad * 4 + r));
            const float inv = 1.0f / lq;
            const int t = tq0 + qg * 16 + quad * 4 + r;
            const size_t rowb = (size_t)(b * SEQ + t) * CDIM + h * 64;
            #pragma unroll
            for (int dt = 0; dt < 4; ++dt)
                Yh[rowb + dt * 16 + lm] = f2bf(O[qg][dt][r] * inv);
        }
}

// ---------------------------------------------------------------------------
extern "C" void kernel_launch(void* const* d_in, const int* in_sizes, int n_in,
                              void* d_out, int out_size, void* d_ws, size_t ws_size,
                              hipStream_t stream)
{
    const float* x     = (const float*)d_in[0];
    const float* Wq    = (const float*)d_in[1];
    const float* Wk    = (const float*)d_in[2];
    const float* Wv    = (const float*)d_in[3];
    const float* Wproj = (const float*)d_in[4];
    float* out = (float*)d_out;

    const int M = 2 * SEQ;   // 4096

    char* p = (char*)d_ws;
    ushort_t* xh   = (ushort_t*)p; p += (size_t)M * CDIM * 2;        // 8 MB, reused as yh
    ushort_t* wqh  = (ushort_t*)p; p += (size_t)CDIM * CDIM * 2;     // 2 MB
    ushort_t* wkh  = (ushort_t*)p; p += (size_t)KVDIM * CDIM * 2;    // 1 MB
    ushort_t* wvh  = (ushort_t*)p; p += (size_t)KVDIM * CDIM * 2;    // 1 MB
    ushort_t* wph  = (ushort_t*)p; p += (size_t)CDIM * CDIM * 2;     // 2 MB
    ushort_t* qh   = (ushort_t*)p; p += (size_t)M * CDIM * 2;        // 8 MB
    ushort_t* kh   = (ushort_t*)p; p += (size_t)M * KVDIM * 2;       // 4 MB
    float*    vbuf = (float*)p;    p += (size_t)M * KVDIM * 4;       // 8 MB
    ushort_t* vth  = (ushort_t*)p; p += (size_t)M * KVDIM * 2;       // 4 MB
    ushort_t* yh = xh;   // x no longer needed once qkv GEMM is done

    dim3 blk(256);

    cvt_bf16<<<dim3(7168), blk, 0, stream>>>(
        x, Wq, Wk, Wv, Wproj, xh, wqh, wkh, wvh, wph);

    // fused q/k/v projections: q bf16*SCL2E, k bf16, v fp32
    gemm128<<<dim3(16, 32), blk, 0, stream>>>(
        xh, CDIM,
        wqh, qh,   CDIM,  3, SCL2E,
        wkh, kh,   KVDIM, 3, 1.0f,
        wvh, vbuf, KVDIM, 0, 1.0f);

    vtrans_kernel<<<dim3(SEQ / 64, 16), blk, 0, stream>>>(vbuf, vth);

    attn4<<<dim3(SEQ / 128, 32), blk, 0, stream>>>(qh, kh, vth, yh);

    gemm128<<<dim3(8, 32), blk, 0, stream>>>(
        yh, CDIM,
        wph, out, CDIM, 0, 1.0f,
        nullptr, nullptr, 0, 0, 1.0f,
        nullptr, nullptr, 0, 0, 1.0f);
}

// Round 4
// 159.930 us; speedup vs baseline: 1.0448x; 1.0448x over previous
//
#include <hip/hip_runtime.h>

// GQA block. B=2, T=2048, C=1024, H=16, KV=8 (GROUP=2), D=64.
// Round 10: revert gemm128 -> gemm64 (R9 regressed); fuse V transpose into
// the V-projection epilogue (epi=2): each lane's acc[mt][nt][0..3] spans 4
// consecutive tokens (m-direction) = the fast axis of vth[(b*8+kv)*64+d][t],
// so one ushort4 store per fragment writes V^T bf16 directly. vtrans kernel
// and the 8 MB fp32 vbuf round-trip are deleted. Bit-identical rounding.
//  - attn4 (KVBLK=128, sigma-permuted K, register-resident P, setprio)
//    unchanged from round 8.

#define SEQ    2048
#define CDIM   1024
#define KVDIM  512
#define SCL2E  0.18033688011112042f   // 0.125 * log2(e)

typedef __attribute__((ext_vector_type(8))) short   bf16x8;
typedef __attribute__((ext_vector_type(4))) float   f32x4;
typedef unsigned short ushort_t;

__device__ __forceinline__ ushort_t f2bf(float f) {
    unsigned u = __float_as_uint(f);
    u += 0x7FFFu + ((u >> 16) & 1u);
    return (ushort_t)(u >> 16);
}
__device__ __forceinline__ float bf2f(ushort_t h) {
    return __uint_as_float(((unsigned)h) << 16);
}
__device__ __forceinline__ void load_lds16(const void* g, void* l) {
    __builtin_amdgcn_global_load_lds(
        (const __attribute__((address_space(1))) void*)g,
        (__attribute__((address_space(3))) void*)l, 16, 0, 0);
}

// ---------------------------------------------------------------------------
// all five inputs -> bf16 hi, one launch. grid 7168 x 256 (exact).
// ---------------------------------------------------------------------------
__global__ __launch_bounds__(256) void cvt_bf16(
    const float* __restrict__ x,  const float* __restrict__ wq,
    const float* __restrict__ wk, const float* __restrict__ wv,
    const float* __restrict__ wp,
    ushort_t* __restrict__ xh,  ushort_t* __restrict__ wqh,
    ushort_t* __restrict__ wkh, ushort_t* __restrict__ wvh,
    ushort_t* __restrict__ wph)
{
    const int i = blockIdx.x * 256 + threadIdx.x;
    const float* src; ushort_t* dst; int off;
    if (i < 1048576)      { src = x;  dst = xh;  off = i; }
    else if (i < 1310720) { src = wq; dst = wqh; off = i - 1048576; }
    else if (i < 1441792) { src = wk; dst = wkh; off = i - 1310720; }
    else if (i < 1572864) { src = wv; dst = wvh; off = i - 1441792; }
    else                  { src = wp; dst = wph; off = i - 1572864; }
    const float4 v = ((const float4*)src)[off];
    ushort4 h;
    h.x = f2bf(v.x); h.y = f2bf(v.y); h.z = f2bf(v.z); h.w = f2bf(v.w);
    ((ushort4*)dst)[off] = h;
}

// ---------------------------------------------------------------------------
// bf16 MFMA GEMM, C = A*B^T, 1 product. Tile 128(M) x 64(N), BK=64, 256 thr.
// Waves 2x2 over tile (64m x 32n each). LDS rows xor-swizzled in 16B chunks
// (inverse swizzle applied on global source side for global_load_lds).
// Up to 3 fused outputs along N. epi: 0 = fp32; 2 = bf16 transposed into
// vth[(b*512 + n)][t] (V^T layout, M must be b*SEQ+t); 3 = bf16 hi * scale.
// ---------------------------------------------------------------------------
__global__ __launch_bounds__(256, 4) void gemm64(
    const ushort_t* __restrict__ A, int K,
    const ushort_t* __restrict__ B1, void* __restrict__ C1, int N1, int epi1, float sc1,
    const ushort_t* __restrict__ B2, void* __restrict__ C2, int N2, int epi2, float sc2,
    const ushort_t* __restrict__ B3, void* __restrict__ C3, int N3, int epi3, float sc3)
{
    __shared__ ushort_t sA[128 * 64];   // 16 KB
    __shared__ ushort_t sB[64 * 64];    // 8 KB

    const int tid = threadIdx.x, wv = tid >> 6, lane = tid & 63;
    const int lm = lane & 15, quad = lane >> 4;
    const int m0 = blockIdx.y * 128;

    const int t1 = N1 >> 6, t2 = N2 >> 6;
    const int bx = blockIdx.x;
    const ushort_t* B; void* Cv; int n0, Nout, epi; float sc;
    if (bx < t1)           { B = B1; Cv = C1; Nout = N1; epi = epi1; sc = sc1; n0 = bx * 64; }
    else if (bx < t1 + t2) { B = B2; Cv = C2; Nout = N2; epi = epi2; sc = sc2; n0 = (bx - t1) * 64; }
    else                   { B = B3; Cv = C3; Nout = N3; epi = epi3; sc = sc3; n0 = (bx - t1 - t2) * 64; }

    const int mh = wv >> 1, nh = wv & 1;
    const int srow = lane >> 3;
    const int scol = ((lane & 7) ^ ((lane >> 3) & 7)) * 8;

    f32x4 acc[4][2] = {};

    for (int k0 = 0; k0 < K; k0 += 64) {
        __syncthreads();
        #pragma unroll
        for (int i = 0; i < 6; ++i) {
            const int g = wv * 6 + i;       // 0..15 -> A groups, 16..23 -> B groups
            if (g < 16)
                load_lds16(A + (size_t)(m0 + g * 8 + srow) * K + k0 + scol, sA + g * 512);
            else
                load_lds16(B + (size_t)(n0 + (g - 16) * 8 + srow) * K + k0 + scol, sB + (g - 16) * 512);
        }
        __syncthreads();

        #pragma unroll
        for (int ks = 0; ks < 2; ++ks) {
            const int co = ((ks * 4 + quad) ^ (lm & 7)) * 8;
            bf16x8 a[4], b[2];
            #pragma unroll
            for (int mt = 0; mt < 4; ++mt)
                a[mt] = *(const bf16x8*)&sA[(mh * 64 + mt * 16 + lm) * 64 + co];
            #pragma unroll
            for (int nt = 0; nt < 2; ++nt)
                b[nt] = *(const bf16x8*)&sB[(nh * 32 + nt * 16 + lm) * 64 + co];
            #pragma unroll
            for (int mt = 0; mt < 4; ++mt)
                #pragma unroll
                for (int nt = 0; nt < 2; ++nt)
                    acc[mt][nt] = __builtin_amdgcn_mfma_f32_16x16x32_bf16(a[mt], b[nt], acc[mt][nt], 0, 0, 0);
        }
    }

    // C/D: row = m + quad*4 + reg, col = n + lm
    if (epi == 0) {
        float* C = (float*)Cv;
        #pragma unroll
        for (int mt = 0; mt < 4; ++mt)
            #pragma unroll
            for (int nt = 0; nt < 2; ++nt)
                #pragma unroll
                for (int r = 0; r < 4; ++r)
                    C[(size_t)(m0 + mh * 64 + mt * 16 + quad * 4 + r) * Nout + n0 + nh * 32 + nt * 16 + lm]
                        = acc[mt][nt][r];
    } else if (epi == 2) {
        // V^T: vth[(b*KVDIM + n)][t], b = m>>11, t = m&2047.
        // Lane's 4 r-values are 4 consecutive t -> one ushort4 store.
        ushort_t* C = (ushort_t*)Cv;
        const int bB   = m0 >> 11;
        const int tloc = (m0 & 2047) + mh * 64 + quad * 4;
        #pragma unroll
        for (int mt = 0; mt < 4; ++mt)
            #pragma unroll
            for (int nt = 0; nt < 2; ++nt) {
                const int n = n0 + nh * 32 + nt * 16 + lm;
                ushort4 u;
                u.x = f2bf(acc[mt][nt][0]);
                u.y = f2bf(acc[mt][nt][1]);
                u.z = f2bf(acc[mt][nt][2]);
                u.w = f2bf(acc[mt][nt][3]);
                *(ushort4*)&C[(size_t)(bB * KVDIM + n) * SEQ + tloc + mt * 16] = u;
            }
    } else {
        ushort_t* C = (ushort_t*)Cv;
        #pragma unroll
        for (int mt = 0; mt < 4; ++mt)
            #pragma unroll
            for (int nt = 0; nt < 2; ++nt)
                #pragma unroll
                for (int r = 0; r < 4; ++r)
                    C[(size_t)(m0 + mh * 64 + mt * 16 + quad * 4 + r) * Nout + n0 + nh * 32 + nt * 16 + lm]
                        = f2bf(acc[mt][nt][r] * sc);
    }
}

// ---------------------------------------------------------------------------
// MFMA flash attention, fixed m=0 softmax, all-bf16 operands, fp32 acc.
// grid (SEQ/128, B*NHEAD), 256 threads. Wave w: q rows [t0+w*32, +32)
// as 2 groups of 16 (Q-hi B-frags in registers, pre-scaled by 0.125*log2e).
// Double-buffered K/V staging, ONE barrier per 128-row K-tile (16 total).
//
// K tile [128 s][64 d], LDS row rho holds global K row sigma(rho):
//   rho bits [sti2 sti1 sti0 q1 q0 r1 r0] -> sigma = [sti2 sti1 q1 q0 sti0 r1 r0]
// so the S^T C-layout delivers exactly the PV A-fragment content: hardware
// k-slot kappa = 32ks+8quad+j holds logical s = kappa. P never leaves
// registers: exp2 -> v_perm bf16-truncate -> packed bf16x8 A operands.
// V tile [64 d][128 s] (16 chunks of 16B per row), chunk stored at
// position c ^ (d&7); inverse applied on global source side.
// ---------------------------------------------------------------------------
__global__ __launch_bounds__(256, 2) void attn4(
    const ushort_t* __restrict__ Qh, const ushort_t* __restrict__ Kh,
    const ushort_t* __restrict__ Vth, ushort_t* __restrict__ Yh)
{
    __shared__ ushort_t sK[2][128 * 64];   // 32 KB
    __shared__ ushort_t sV[2][64 * 128];   // 32 KB

    const int tid = threadIdx.x, wv = tid >> 6, lane = tid & 63;
    const int lm = lane & 15, quad = lane >> 4;
    const int b = blockIdx.y >> 4, h = blockIdx.y & 15, kvh = h >> 1;
    const int t0 = blockIdx.x * 128, tq0 = t0 + wv * 32;

    // persistent Q B-frags: n = q = lm (per group), k = d = ks*32 + quad*8 + j
    bf16x8 qh[2][2];
    #pragma unroll
    for (int qg = 0; qg < 2; ++qg) {
        const size_t rb = (size_t)(b * SEQ + tq0 + qg * 16 + lm) * CDIM + h * 64;
        #pragma unroll
        for (int ks = 0; ks < 2; ++ks)
            qh[qg][ks] = *(const bf16x8*)(Qh + rb + ks * 32 + quad * 8);
    }

    const ushort_t* gK = Kh  + (size_t)b * SEQ * KVDIM + kvh * 64;
    const ushort_t* gV = Vth + (size_t)(b * 8 + kvh) * 64 * SEQ;

    const int g0 = (wv & 1) * 8;          // group base within this wave's half

    // K staging lane geometry: 16 groups of (8 rows x 64 cols) = 512 ushorts
    const int srow = lane >> 3;           // 0..7 row within group
    const int scol = ((lane & 7) ^ ((lane >> 3) & 7)) * 8;  // swizzled 16B chunk

    // sigma-permuted source rows for K staging (LDS row -> global row)
    int krow[8];
    #pragma unroll
    for (int it = 0; it < 8; ++it) {
        const int lr = (g0 + it) * 8 + srow;   // 0..127
        krow[it] = (lr & 0x60) | ((lr & 0x10) >> 2) | ((lr & 0x0C) << 1) | (lr & 3);
    }

    // V staging lane geometry: 16 groups of (4 rows x 128 cols) = 512 ushorts
    const int vrow = lane >> 4;           // 0..3 row (d) within group
    const int vpos = lane & 15;           // 16B chunk position within row

    float l_a[2] = {0.0f, 0.0f}, l_b[2] = {0.0f, 0.0f};
    f32x4 O[2][4] = {};

    // preload tile 0 into buffer 0
    if (wv < 2) {
        #pragma unroll
        for (int it = 0; it < 8; ++it)
            load_lds16(gK + (size_t)krow[it] * KVDIM + scol,
                       &sK[0][(g0 + it) * 512]);
    } else {
        #pragma unroll
        for (int it = 0; it < 8; ++it) {
            const int d = (g0 + it) * 4 + vrow;
            load_lds16(gV + (size_t)d * SEQ + (vpos ^ (d & 7)) * 8,
                       &sV[0][(g0 + it) * 512]);
        }
    }

    typedef union { bf16x8 v; unsigned u[4]; } pku;

    for (int kt = 0; kt < SEQ / 128; ++kt) {
        const int cur = kt & 1;
        __syncthreads();   // tile kt landed; all waves done with buf cur^1

        if (kt + 1 < SEQ / 128) {
            const int s1 = (kt + 1) * 128;
            if (wv < 2) {
                #pragma unroll
                for (int it = 0; it < 8; ++it)
                    load_lds16(gK + (size_t)(s1 + krow[it]) * KVDIM + scol,
                               &sK[cur ^ 1][(g0 + it) * 512]);
            } else {
                #pragma unroll
                for (int it = 0; it < 8; ++it) {
                    const int d = (g0 + it) * 4 + vrow;
                    load_lds16(gV + (size_t)d * SEQ + s1 + (vpos ^ (d & 7)) * 8,
                               &sV[cur ^ 1][(g0 + it) * 512]);
                }
            }
        }

        // S^T = K Q^T : col = q = lm, row(lds) = sti*16 + quad*4 + r,
        // logical s = sigma(row)
        f32x4 st[2][8] = {};
        __builtin_amdgcn_s_setprio(1);
        #pragma unroll
        for (int sti = 0; sti < 8; ++sti)
            #pragma unroll
            for (int ks = 0; ks < 2; ++ks) {
                const int off = (sti * 16 + lm) * 64 + (((ks * 4 + quad) ^ (lm & 7)) * 8);
                const bf16x8 kf = *(const bf16x8*)&sK[cur][off];
                #pragma unroll
                for (int qg = 0; qg < 2; ++qg)
                    st[qg][sti] = __builtin_amdgcn_mfma_f32_16x16x32_bf16(kf, qh[qg][ks], st[qg][sti], 0, 0, 0);
            }
        __builtin_amdgcn_s_setprio(0);

        // P = exp2(S'), accumulate l, pack bf16 (truncate via v_perm)
        // directly into PV A-frags: pa[ks] elem j = 4*(sti&1)+r <- st[2ks+(sti&1)][r]
        pku pa[2][4];
        #pragma unroll
        for (int qg = 0; qg < 2; ++qg)
            #pragma unroll
            for (int sti = 0; sti < 8; ++sti) {
                const float p0 = __builtin_amdgcn_exp2f(st[qg][sti][0]);
                const float p1 = __builtin_amdgcn_exp2f(st[qg][sti][1]);
                const float p2 = __builtin_amdgcn_exp2f(st[qg][sti][2]);
                const float p3 = __builtin_amdgcn_exp2f(st[qg][sti][3]);
                if (sti & 1) l_b[qg] += (p0 + p1) + (p2 + p3);
                else         l_a[qg] += (p0 + p1) + (p2 + p3);
                pa[qg][sti >> 1].u[(sti & 1) * 2 + 0] =
                    __builtin_amdgcn_perm(__float_as_uint(p1), __float_as_uint(p0), 0x07060302u);
                pa[qg][sti >> 1].u[(sti & 1) * 2 + 1] =
                    __builtin_amdgcn_perm(__float_as_uint(p3), __float_as_uint(p2), 0x07060302u);
            }

        // O += P V : A = P (m=q, k-slot kappa holds s=kappa), B = V^T (n=d)
        __builtin_amdgcn_s_setprio(1);
        #pragma unroll
        for (int ks = 0; ks < 4; ++ks) {
            const int co = ((ks * 4 + quad) ^ (lm & 7)) * 8;
            #pragma unroll
            for (int dt = 0; dt < 4; ++dt) {
                const bf16x8 vt = *(const bf16x8*)&sV[cur][(dt * 16 + lm) * 128 + co];
                #pragma unroll
                for (int qg = 0; qg < 2; ++qg)
                    O[qg][dt] = __builtin_amdgcn_mfma_f32_16x16x32_bf16(pa[qg][ks].v, vt, O[qg][dt], 0, 0, 0);
            }
        }
        __builtin_amdgcn_s_setprio(0);
    }

    // l: reduce across quads (disjoint 32-row s slices per quad; sigma is a
    // bijection so coverage of each 128-row tile is exact)
    float l_r[2];
    #pragma unroll
    for (int qg = 0; qg < 2; ++qg) {
        l_r[qg] = l_a[qg] + l_b[qg];
        l_r[qg] += __shfl_xor(l_r[qg], 16);
        l_r[qg] += __shfl_xor(l_r[qg], 32);
    }
    // O C-layout: col = d = dt*16 + lm, row = q = qg*16 + quad*4 + r
    #pragma unroll
    for (int qg = 0; qg < 2; ++qg)
        #pragma unroll
        for (int r = 0; r < 4; ++r) {
            const float lq = __shfl(l_r[qg], (lane & 48) | (quad * 4 + r));
            const float inv = 1.0f / lq;
            const int t = tq0 + qg * 16 + quad * 4 + r;
            const size_t rowb = (size_t)(b * SEQ + t) * CDIM + h * 64;
            #pragma unroll
            for (int dt = 0; dt < 4; ++dt)
                Yh[rowb + dt * 16 + lm] = f2bf(O[qg][dt][r] * inv);
        }
}

// ---------------------------------------------------------------------------
extern "C" void kernel_launch(void* const* d_in, const int* in_sizes, int n_in,
                              void* d_out, int out_size, void* d_ws, size_t ws_size,
                              hipStream_t stream)
{
    const float* x     = (const float*)d_in[0];
    const float* Wq    = (const float*)d_in[1];
    const float* Wk    = (const float*)d_in[2];
    const float* Wv    = (const float*)d_in[3];
    const float* Wproj = (const float*)d_in[4];
    float* out = (float*)d_out;

    const int M = 2 * SEQ;   // 4096

    char* p = (char*)d_ws;
    ushort_t* xh   = (ushort_t*)p; p += (size_t)M * CDIM * 2;        // 8 MB, reused as yh
    ushort_t* wqh  = (ushort_t*)p; p += (size_t)CDIM * CDIM * 2;     // 2 MB
    ushort_t* wkh  = (ushort_t*)p; p += (size_t)KVDIM * CDIM * 2;    // 1 MB
    ushort_t* wvh  = (ushort_t*)p; p += (size_t)KVDIM * CDIM * 2;    // 1 MB
    ushort_t* wph  = (ushort_t*)p; p += (size_t)CDIM * CDIM * 2;     // 2 MB
    ushort_t* qh   = (ushort_t*)p; p += (size_t)M * CDIM * 2;        // 8 MB
    ushort_t* kh   = (ushort_t*)p; p += (size_t)M * KVDIM * 2;       // 4 MB
    ushort_t* vth  = (ushort_t*)p; p += (size_t)M * KVDIM * 2;       // 4 MB
    ushort_t* yh = xh;   // x no longer needed once qkv GEMM is done

    dim3 blk(256);

    cvt_bf16<<<dim3(7168), blk, 0, stream>>>(
        x, Wq, Wk, Wv, Wproj, xh, wqh, wkh, wvh, wph);

    // fused q/k/v projections: q bf16*SCL2E, k bf16, v bf16 transposed (V^T)
    gemm64<<<dim3(32, 32), blk, 0, stream>>>(
        xh, CDIM,
        wqh, qh,  CDIM,  3, SCL2E,
        wkh, kh,  KVDIM, 3, 1.0f,
        wvh, vth, KVDIM, 2, 1.0f);

    attn4<<<dim3(SEQ / 128, 32), blk, 0, stream>>>(qh, kh, vth, yh);

    gemm64<<<dim3(16, 32), blk, 0, stream>>>(
        yh, CDIM,
        wph, out, CDIM, 0, 1.0f,
        nullptr, nullptr, 0, 0, 1.0f,
        nullptr, nullptr, 0, 0, 1.0f);
}